// Round 8
// baseline (334.766 us; speedup 1.0000x reference)
//
#include <hip/hip_runtime.h>
#include <hip/hip_bf16.h>

typedef unsigned short u16;
typedef unsigned int   u32;
typedef _Float16 f16;
typedef __attribute__((ext_vector_type(4))) float f32x4;
typedef __attribute__((ext_vector_type(8))) short s16x8;
typedef __attribute__((ext_vector_type(8))) f16 f16x8;
typedef __attribute__((ext_vector_type(2))) __fp16 fp16x2;
typedef __attribute__((ext_vector_type(4))) u16 u16x4;
typedef __attribute__((ext_vector_type(2))) u32 u32x2;

#define DI __device__ __forceinline__

static constexpr int Bb = 2, Ss = 2048, Hh = 16, Dd = 64, Ee = 1024;
static constexpr int Mrows = Bb * Ss;              // 4096
static constexpr size_t NE = (size_t)Mrows * Ee;   // 4 M elems
static constexpr size_t WN = (size_t)Ee * Ee;      // 1 M elems
static constexpr float QSCALE = 0.125f * 1.44269504088896f;  // 1/8 * log2(e)

DI float bf2f(u16 h) { u32 u = ((u32)h) << 16; return __builtin_bit_cast(float, u); }
DI u16 f2bf(float f) {
    u32 u = __builtin_bit_cast(u32, f);
    u32 r = (u + 0x7FFFu + ((u >> 16) & 1u)) >> 16;
    return (u16)r;
}
DI u16 f2h(float f) { f16 h = (f16)f; return __builtin_bit_cast(u16, h); }
DI u32 pkrtz(float a, float b) {
    fp16x2 r = __builtin_amdgcn_cvt_pkrtz(a, b);
    return __builtin_bit_cast(u32, r);
}
DI float ex2(float x) { return __builtin_amdgcn_exp2f(x); }

#define MFMA_BF(a, b, c) __builtin_amdgcn_mfma_f32_16x16x32_bf16((a), (b), (c), 0, 0, 0)
#define MFMA_F16(a, b, c) __builtin_amdgcn_mfma_f32_16x16x32_f16( \
    __builtin_bit_cast(f16x8, (a)), __builtin_bit_cast(f16x8, (b)), (c), 0, 0, 0)

// async global->LDS, 16B per lane (LDS dest must be lane-linear)
DI void gld16(const u16* g, u16* l) {
    __builtin_amdgcn_global_load_lds((const __attribute__((address_space(1))) void*)g,
                                     (__attribute__((address_space(3))) void*)l, 16, 0, 0);
}

// ---------------- prep: q,k -> bf16 hi/lo; v -> fp16 ----------------
__global__ __launch_bounds__(256) void k_split3(
    const float* __restrict__ q, const float* __restrict__ k, const float* __restrict__ v,
    u16* __restrict__ qh, u16* __restrict__ ql,
    u16* __restrict__ kh, u16* __restrict__ kl, u16* __restrict__ vh) {
    int i = blockIdx.x * 256 + threadIdx.x;
    int y = blockIdx.y;
    if (y == 2) { vh[i] = f2h(v[i]); return; }
    const float* s = y ? k : q;
    u16* h = y ? kh : qh;
    u16* l = y ? kl : ql;
    float val = s[i];
    u16 hh = f2bf(val);
    h[i] = hh;
    l[i] = f2bf(val - bf2f(hh));
}

// ---------------- prep: weights -> B^T [N][K] via LDS-tiled transpose ----------------
__global__ __launch_bounds__(256) void k_wprep(
    const float* __restrict__ Wq, const float* __restrict__ Wk,
    const float* __restrict__ Wv, const float* __restrict__ Wo,
    u16* __restrict__ WqTh, u16* __restrict__ WqTl,
    u16* __restrict__ WkTh, u16* __restrict__ WkTl,
    u16* __restrict__ WvT, u16* __restrict__ WoT) {
    __shared__ float Ts[64 * 65];
    const int y = blockIdx.y;
    const int ti = blockIdx.x >> 4, tj = blockIdx.x & 15;   // n-tile, k-tile
    const float* W = (y == 0) ? Wq : (y == 1) ? Wk : (y == 2) ? Wv : Wo;
    const int t = threadIdx.x;
    const int col = t & 63, rb = (t >> 6) * 16;
#pragma unroll
    for (int rr = 0; rr < 16; rr++) {
        int row = rb + rr;   // k-local
        float v = (y < 3) ? W[(size_t)ti * 65536 + (size_t)(tj * 64 + row) * 64 + col]
                          : W[(size_t)(tj * 64 + row) * Ee + ti * 64 + col];
        Ts[row * 65 + col] = v;
    }
    __syncthreads();
#pragma unroll
    for (int rr = 0; rr < 16; rr++) {
        int orow = rb + rr;  // n-local
        int ocol = col;      // k-local (coalesced)
        float v = Ts[ocol * 65 + orow];
        size_t oidx = (size_t)(ti * 64 + orow) * Ee + tj * 64 + ocol;
        if (y == 0) {
            u16 hh = f2bf(v); WqTh[oidx] = hh; WqTl[oidx] = f2bf(v - bf2f(hh));
        } else if (y == 1) {
            u16 hh = f2bf(v); WkTh[oidx] = hh; WkTl[oidx] = f2bf(v - bf2f(hh));
        } else if (y == 2) {
            WvT[oidx] = f2h(v);
        } else {
            WoT[oidx] = f2h(v);
        }
    }
}

// ---------------- GEMM body, 64(M) x 128(N) tile ----------------
// SPLIT=1: bf16 hi/lo 3-MFMA. F16=1: fp16 MFMA.
// OUTMODE: 0 = f32 row-major, 1 = fp16 transposed [N][M], 2 = bf16 hi/lo row-major.
template <int SPLIT, int F16, int OUTMODE>
DI void gemm_body(const u16* __restrict__ Ah, const u16* __restrict__ Al,
                  const u16* __restrict__ Bh, const u16* __restrict__ Bl,
                  const float* __restrict__ bias,
                  u16* __restrict__ C16h, u16* __restrict__ C16l, float* __restrict__ Cf,
                  float scale, u16* As0, u16* As1, u16* Bs0, u16* Bs1) {
    constexpr int M = Mrows, N = Ee, K = Ee;
    const int tid = threadIdx.x;
    const int wave = tid >> 6, lane = tid & 63;
    const int quad = lane >> 4, l16 = lane & 15;
    const int m0 = blockIdx.y * 64, n0 = blockIdx.x * 128;
    const int wm = (wave >> 1) * 32, wn = (wave & 1) * 64;

    f32x4 acc[2][4];
#pragma unroll
    for (int i = 0; i < 2; i++)
#pragma unroll
        for (int j = 0; j < 4; j++) acc[i][j] = (f32x4)0.0f;

    for (int kk = 0; kk < K; kk += 32) {
        __syncthreads();
        {   // A tile: 64 rows x 32 k = 256 chunks of 16B (lane-linear)
            int c = tid;
            int row = c >> 2, j = c & 3;
            size_t ga = (size_t)(m0 + row) * K + kk + j * 8;
            gld16(Ah + ga, As0 + c * 8);
            if constexpr (SPLIT) gld16(Al + ga, As1 + c * 8);
        }
#pragma unroll
        for (int i = 0; i < 2; i++) {  // B tile: 128 rows x 32 k = 512 chunks
            int c = tid + i * 256;
            int row = c >> 2, j = c & 3;
            size_t gb = (size_t)(n0 + row) * K + kk + j * 8;
            gld16(Bh + gb, Bs0 + c * 8);
            if constexpr (SPLIT) gld16(Bl + gb, Bs1 + c * 8);
        }
        __syncthreads();

        s16x8 af[2][2], bf[4][2];
#pragma unroll
        for (int mt = 0; mt < 2; mt++) {
            int r = wm + mt * 16 + l16;
            af[mt][0] = *(const s16x8*)&As0[r * 32 + quad * 8];
            if constexpr (SPLIT) af[mt][1] = *(const s16x8*)&As1[r * 32 + quad * 8];
        }
#pragma unroll
        for (int nt = 0; nt < 4; nt++) {
            int r = wn + nt * 16 + l16;
            bf[nt][0] = *(const s16x8*)&Bs0[r * 32 + quad * 8];
            if constexpr (SPLIT) bf[nt][1] = *(const s16x8*)&Bs1[r * 32 + quad * 8];
        }
#pragma unroll
        for (int mt = 0; mt < 2; mt++)
#pragma unroll
            for (int nt = 0; nt < 4; nt++) {
                if constexpr (F16) {
                    acc[mt][nt] = MFMA_F16(af[mt][0], bf[nt][0], acc[mt][nt]);
                } else {
                    acc[mt][nt] = MFMA_BF(af[mt][0], bf[nt][0], acc[mt][nt]);
                    if constexpr (SPLIT) {
                        acc[mt][nt] = MFMA_BF(af[mt][0], bf[nt][1], acc[mt][nt]);
                        acc[mt][nt] = MFMA_BF(af[mt][1], bf[nt][0], acc[mt][nt]);
                    }
                }
            }
    }

    // epilogue — C/D layout: col = lane&15, row = quad*4 + reg
#pragma unroll
    for (int mt = 0; mt < 2; mt++)
#pragma unroll
        for (int nt = 0; nt < 4; nt++) {
            int gn = n0 + wn + nt * 16 + l16;
            float bs = bias[gn];
            if constexpr (OUTMODE == 1) {
                int gm = m0 + wm + mt * 16 + quad * 4;
                u16x4 pk;
#pragma unroll
                for (int r = 0; r < 4; r++) pk[r] = f2h((acc[mt][nt][r] + bs) * scale);
                *(u16x4*)&C16h[(size_t)gn * M + gm] = pk;
            } else {
#pragma unroll
                for (int r = 0; r < 4; r++) {
                    int gm = m0 + wm + mt * 16 + quad * 4 + r;
                    float v = (acc[mt][nt][r] + bs) * scale;
                    if constexpr (OUTMODE == 0) {
                        Cf[(size_t)gm * N + gn] = v;
                    } else {
                        u16 hh = f2bf(v);
                        C16h[(size_t)gm * N + gn] = hh;
                        C16l[(size_t)gm * N + gn] = f2bf(v - bf2f(hh));
                    }
                }
            }
        }
}

// ---------------- fused Q/K/V projections (grid.z selects) ----------------
__global__ __launch_bounds__(256, 4) void k_qkv(
    const u16* __restrict__ qh, const u16* __restrict__ ql,
    const u16* __restrict__ kh, const u16* __restrict__ kl,
    const u16* __restrict__ vh,
    const u16* __restrict__ WqTh, const u16* __restrict__ WqTl,
    const u16* __restrict__ WkTh, const u16* __restrict__ WkTl,
    const u16* __restrict__ WvT,
    const float* __restrict__ bq, const float* __restrict__ bk, const float* __restrict__ bv,
    u16* __restrict__ Qh, u16* __restrict__ Ql2,
    u16* __restrict__ Kh, u16* __restrict__ Kl2, u16* __restrict__ Vt) {
    __shared__ u16 As[2][64 * 32];
    __shared__ u16 Bs[2][128 * 32];
    int z = blockIdx.z;
    if (z == 0)
        gemm_body<1, 0, 2>(qh, ql, WqTh, WqTl, bq, Qh, Ql2, nullptr, QSCALE,
                           As[0], As[1], Bs[0], Bs[1]);
    else if (z == 1)
        gemm_body<1, 0, 2>(kh, kl, WkTh, WkTl, bk, Kh, Kl2, nullptr, 1.0f,
                           As[0], As[1], Bs[0], Bs[1]);
    else
        gemm_body<0, 1, 1>(vh, nullptr, WvT, nullptr, bv, Vt, nullptr, nullptr, 1.0f,
                           As[0], As[1], Bs[0], Bs[1]);
}

// ---------------- output projection: ctx(fp16) @ WoT(fp16) + bo -> f32 ----------------
__global__ __launch_bounds__(256, 4) void k_out(
    const u16* __restrict__ ctx, const u16* __restrict__ WoT,
    const float* __restrict__ bo, float* __restrict__ out) {
    __shared__ u16 As[64 * 32];
    __shared__ u16 Bs[128 * 32];
    gemm_body<0, 1, 0>(ctx, nullptr, WoT, nullptr, bo, nullptr, nullptr, out, 1.0f,
                       As, nullptr, Bs, nullptr);
}

// ---------------- flash attention, 2x2 wave tiling ----------------
// Block = 64 q x 64 t per iter, 4 waves as 2(t) x 2(q): wave (tw,qw) owns
// t in [tw*32,+32), q in [qw*32,+32). Each wave reads only half of Ks/Vs
// (round-7 diagnosis: LDS-pipe bound, 64 KB/blk-iter of QK A-reads).
// Q hi/lo loop-invariant in regs. Softmax stats cross-wave-reduced via 512 B
// LDS buffers (2 extra barriers/iter). O partial over t, reduced once at end.
// Score path: bf16 hi/lo split (round-5: fp16 scores -> absmax 432). exp2 domain.
// Grid: x = bh (XCD = bh%8 -> per-XCD K/V working set ~3 MB ~ L2), y = q-tile.
__global__ __launch_bounds__(256, 4) void k_attn(
    const u16* __restrict__ Qh, const u16* __restrict__ Ql,
    const u16* __restrict__ Kh, const u16* __restrict__ Kl,
    const u16* __restrict__ Vt, u16* __restrict__ ctx) {
    const int bh = blockIdx.x;
    const int b = bh >> 4, h = bh & 15;
    const int q0 = blockIdx.y * 64;
    const int rowBase = b * Ss + q0;
    const int hc = h * 64;

    __shared__ u16 Ks[2][64 * 64];     // [t][d] bf16 hi/lo, xor-swizzled chunks (16 KB)
    __shared__ u16 Vs[64 * 64];        // [d][t] fp16, xor-swizzled chunks (8 KB)
    __shared__ u16 Pw[4][32 * 40];     // per-wave [q-local 32][t-local 32], pad 40 (10 KB)
    __shared__ float Sred[2][128];     // [max/sum][q*2 + tw] (1 KB)

    const int tid = threadIdx.x;
    const int wave = tid >> 6, lane = tid & 63;
    const int quad = lane >> 4, l16 = lane & 15;
    const int tw = wave >> 1, qw = wave & 1;

    // loop-invariant Q B-frags bq[nt][kc][hl] (lane n = q, k-contiguous 16B)
    s16x8 bq[2][2][2];
#pragma unroll
    for (int nt = 0; nt < 2; nt++) {
        int row = rowBase + qw * 32 + nt * 16 + l16;
#pragma unroll
        for (int kc = 0; kc < 2; kc++) {
            bq[nt][kc][0] = *(const s16x8*)(Qh + (size_t)row * Ee + hc + kc * 32 + quad * 8);
            bq[nt][kc][1] = *(const s16x8*)(Ql + (size_t)row * Ee + hc + kc * 32 + quad * 8);
        }
    }

    f32x4 o[4][2];   // [dg][nt]: O[d=dg*16+quad*4+r][q], partial over this wave's t
#pragma unroll
    for (int dg = 0; dg < 4; dg++)
#pragma unroll
        for (int nt = 0; nt < 2; nt++) o[dg][nt] = (f32x4)0.0f;
    float m_[2] = {-1e30f, -1e30f};
    float l_[2] = {0.f, 0.f};

    for (int t0 = 0; t0 < Ss; t0 += 64) {
        const int kRowBase = b * Ss + t0;
        __syncthreads();
#pragma unroll
        for (int i = 0; i < 2; i++) {
            int c = tid + i * 256;
            int row = c >> 3, j = c & 7;
            int sj = j ^ (row & 7);
            *(s16x8*)&Ks[0][row * 64 + sj * 8] =
                *(const s16x8*)(Kh + (size_t)(kRowBase + row) * Ee + hc + j * 8);
            *(s16x8*)&Ks[1][row * 64 + sj * 8] =
                *(const s16x8*)(Kl + (size_t)(kRowBase + row) * Ee + hc + j * 8);
            *(s16x8*)&Vs[row * 64 + sj * 8] =
                *(const s16x8*)(Vt + (size_t)(hc + row) * Mrows + kRowBase + j * 8);
        }
        __syncthreads();

        // S^T = K·Q^T (split); st[mt][nt]: t = tw*32 + mt*16 + quad*4 + r,
        // q = qw*32 + nt*16 + l16
        f32x4 st[2][2];
#pragma unroll
        for (int mt = 0; mt < 2; mt++)
#pragma unroll
            for (int nt = 0; nt < 2; nt++) st[mt][nt] = (f32x4)0.0f;
#pragma unroll
        for (int mt = 0; mt < 2; mt++) {
            int tr = tw * 32 + mt * 16 + l16;
#pragma unroll
            for (int kc = 0; kc < 2; kc++) {
                int sj = (kc * 4 + quad) ^ (l16 & 7);
                s16x8 akh = *(const s16x8*)&Ks[0][tr * 64 + sj * 8];
                s16x8 akl = *(const s16x8*)&Ks[1][tr * 64 + sj * 8];
#pragma unroll
                for (int nt = 0; nt < 2; nt++) {
                    st[mt][nt] = MFMA_BF(akh, bq[nt][kc][0], st[mt][nt]);
                    st[mt][nt] = MFMA_BF(akh, bq[nt][kc][1], st[mt][nt]);
                    st[mt][nt] = MFMA_BF(akl, bq[nt][kc][0], st[mt][nt]);
                }
            }
        }

        // wave-partial max per q, cross-wave (tw pair) via LDS
#pragma unroll
        for (int nt = 0; nt < 2; nt++) {
            float a = fmaxf(fmaxf(st[0][nt][0], st[0][nt][1]), fmaxf(st[0][nt][2], st[0][nt][3]));
            float c = fmaxf(fmaxf(st[1][nt][0], st[1][nt][1]), fmaxf(st[1][nt][2], st[1][nt][3]));
            float pm = fmaxf(a, c);
            pm = fmaxf(pm, __shfl_xor(pm, 16));
            pm = fmaxf(pm, __shfl_xor(pm, 32));
            if (quad == 0) Sred[0][(qw * 32 + nt * 16 + l16) * 2 + tw] = pm;
        }
        __syncthreads();
        float al[2];
#pragma unroll
        for (int nt = 0; nt < 2; nt++) {
            float2 mp = *(const float2*)&Sred[0][(qw * 32 + nt * 16 + l16) * 2];
            float mnew = fmaxf(m_[nt], fmaxf(mp.x, mp.y));
            al[nt] = ex2(m_[nt] - mnew);
            m_[nt] = mnew;
        }
        // exp + pack P (wave-private LDS) + partial sum, cross-wave sum via LDS
#pragma unroll
        for (int nt = 0; nt < 2; nt++) {
            float ps = 0.f;
#pragma unroll
            for (int mt = 0; mt < 2; mt++) {
                float p0 = ex2(st[mt][nt][0] - m_[nt]);
                float p1 = ex2(st[mt][nt][1] - m_[nt]);
                float p2 = ex2(st[mt][nt][2] - m_[nt]);
                float p3 = ex2(st[mt][nt][3] - m_[nt]);
                ps += (p0 + p1) + (p2 + p3);
                u32x2 pk;
                pk[0] = pkrtz(p0, p1);
                pk[1] = pkrtz(p2, p3);
                *(u32x2*)&Pw[wave][(nt * 16 + l16) * 40 + mt * 16 + quad * 4] = pk;
            }
            ps += __shfl_xor(ps, 16);
            ps += __shfl_xor(ps, 32);
            if (quad == 0) Sred[1][(qw * 32 + nt * 16 + l16) * 2 + tw] = ps;
        }
        __syncthreads();
#pragma unroll
        for (int nt = 0; nt < 2; nt++) {
            float2 sp = *(const float2*)&Sred[1][(qw * 32 + nt * 16 + l16) * 2];
            l_[nt] = l_[nt] * al[nt] + (sp.x + sp.y);
#pragma unroll
            for (int dg = 0; dg < 4; dg++) o[dg][nt] *= al[nt];
        }

        // O^T(partial) += V^T[d][t-range 32] · P^T[t-range][q]  (K=32, one MFMA per dg,nt)
        s16x8 bp[2];
#pragma unroll
        for (int nt = 0; nt < 2; nt++)
            bp[nt] = *(const s16x8*)&Pw[wave][(nt * 16 + l16) * 40 + quad * 8];
#pragma unroll
        for (int dg = 0; dg < 4; dg++) {
            int sj = (tw * 4 + quad) ^ (l16 & 7);
            s16x8 av = *(const s16x8*)&Vs[(dg * 16 + l16) * 64 + sj * 8];
#pragma unroll
            for (int nt = 0; nt < 2; nt++) o[dg][nt] = MFMA_F16(av, bp[nt], o[dg][nt]);
        }
    }

    // cross-wave O reduction (tw=1 -> LDS, tw=0 adds), then epilogue
    __syncthreads();
    float* Ored = (float*)&Ks[0][0];   // 16 KB alias, safe after barrier
    if (tw == 1) {
#pragma unroll
        for (int dg = 0; dg < 4; dg++)
#pragma unroll
            for (int nt = 0; nt < 2; nt++)
                *(f32x4*)&Ored[(((qw * 4 + dg) * 2 + nt) * 64 + lane) * 4] = o[dg][nt];
    }
    __syncthreads();
    if (tw == 0) {
        float inv[2] = {1.0f / l_[0], 1.0f / l_[1]};
#pragma unroll
        for (int dg = 0; dg < 4; dg++)
#pragma unroll
            for (int nt = 0; nt < 2; nt++) {
                f32x4 op = *(const f32x4*)&Ored[(((qw * 4 + dg) * 2 + nt) * 64 + lane) * 4];
                f32x4 ov = o[dg][nt] + op;
                int gm = rowBase + qw * 32 + nt * 16 + l16;
                u32x2 pk;
                pk[0] = pkrtz(ov[0] * inv[nt], ov[1] * inv[nt]);
                pk[1] = pkrtz(ov[2] * inv[nt], ov[3] * inv[nt]);
                *(u32x2*)&ctx[(size_t)gm * Ee + hc + dg * 16 + quad * 4] = pk;
            }
    }
}

extern "C" void kernel_launch(void* const* d_in, const int* in_sizes, int n_in,
                              void* d_out, int out_size, void* d_ws, size_t ws_size,
                              hipStream_t stream) {
    const float* q   = (const float*)d_in[0];
    const float* kin = (const float*)d_in[1];
    const float* v   = (const float*)d_in[2];
    const float* Wq  = (const float*)d_in[3];
    const float* Wk  = (const float*)d_in[4];
    const float* Wv  = (const float*)d_in[5];
    const float* bq  = (const float*)d_in[6];
    const float* bk  = (const float*)d_in[7];
    const float* bv  = (const float*)d_in[8];
    const float* Wo  = (const float*)d_in[9];
    const float* bo  = (const float*)d_in[10];

    u16* ws = (u16*)d_ws;
    u16 *qh = ws,          *ql = ws + NE,     *kh = ws + 2 * NE, *kl = ws + 3 * NE;
    u16 *vh = ws + 4 * NE;
    u16 *Qh = ws + 5 * NE, *Ql = ws + 6 * NE, *Kh = ws + 7 * NE, *Kl = ws + 8 * NE;
    u16 *Vt = ws + 9 * NE, *ctx = ws + 10 * NE;
    u16 *WqTh = ws + 11 * NE;
    u16 *WqTl = WqTh + WN, *WkTh = WqTh + 2 * WN, *WkTl = WqTh + 3 * WN;
    u16 *WvT = WqTh + 4 * WN, *WoT = WqTh + 5 * WN;

    dim3 b256(256);
    k_split3<<<dim3(NE / 256, 3), b256, 0, stream>>>(q, kin, v, qh, ql, kh, kl, vh);
    k_wprep<<<dim3(256, 4), b256, 0, stream>>>(Wq, Wk, Wv, Wo,
                                               WqTh, WqTl, WkTh, WkTl, WvT, WoT);

    k_qkv<<<dim3(8, 64, 3), b256, 0, stream>>>(qh, ql, kh, kl, vh,
                                               WqTh, WqTl, WkTh, WkTl, WvT,
                                               bq, bk, bv, Qh, Ql, Kh, Kl, Vt);

    k_attn<<<dim3(Bb * Hh, Ss / 64), b256, 0, stream>>>(Qh, Ql, Kh, Kl, Vt, ctx);

    k_out<<<dim3(8, 64), b256, 0, stream>>>(ctx, WoT, bo, (float*)d_out);
}

// Round 9
// 318.995 us; speedup vs baseline: 1.0494x; 1.0494x over previous
//
#include <hip/hip_runtime.h>
#include <hip/hip_bf16.h>

typedef unsigned short u16;
typedef unsigned int   u32;
typedef _Float16 f16;
typedef __attribute__((ext_vector_type(4))) float f32x4;
typedef __attribute__((ext_vector_type(8))) short s16x8;
typedef __attribute__((ext_vector_type(8))) f16 f16x8;
typedef __attribute__((ext_vector_type(2))) __fp16 fp16x2;
typedef __attribute__((ext_vector_type(4))) u16 u16x4;
typedef __attribute__((ext_vector_type(2))) u32 u32x2;

#define DI __device__ __forceinline__

static constexpr int Bb = 2, Ss = 2048, Hh = 16, Dd = 64, Ee = 1024;
static constexpr int Mrows = Bb * Ss;              // 4096
static constexpr size_t NE = (size_t)Mrows * Ee;   // 4 M elems
static constexpr size_t WN = (size_t)Ee * Ee;      // 1 M elems
static constexpr float QSCALE = 0.125f * 1.44269504088896f;  // 1/8 * log2(e)

DI float bf2f(u16 h) { u32 u = ((u32)h) << 16; return __builtin_bit_cast(float, u); }
DI u16 f2bf(float f) {
    u32 u = __builtin_bit_cast(u32, f);
    u32 r = (u + 0x7FFFu + ((u >> 16) & 1u)) >> 16;
    return (u16)r;
}
DI u16 f2h(float f) { f16 h = (f16)f; return __builtin_bit_cast(u16, h); }
DI u32 pkrtz(float a, float b) {
    fp16x2 r = __builtin_amdgcn_cvt_pkrtz(a, b);
    return __builtin_bit_cast(u32, r);
}
DI float ex2(float x) { return __builtin_amdgcn_exp2f(x); }

#define MFMA_BF(a, b, c) __builtin_amdgcn_mfma_f32_16x16x32_bf16((a), (b), (c), 0, 0, 0)
#define MFMA_F16(a, b, c) __builtin_amdgcn_mfma_f32_16x16x32_f16( \
    __builtin_bit_cast(f16x8, (a)), __builtin_bit_cast(f16x8, (b)), (c), 0, 0, 0)

// async global->LDS, 16B per lane (LDS dest must be lane-linear)
DI void gld16(const u16* g, u16* l) {
    __builtin_amdgcn_global_load_lds((const __attribute__((address_space(1))) void*)g,
                                     (__attribute__((address_space(3))) void*)l, 16, 0, 0);
}

// ---------------- prep: q,k -> bf16 hi/lo; v -> fp16 ----------------
__global__ __launch_bounds__(256) void k_split3(
    const float* __restrict__ q, const float* __restrict__ k, const float* __restrict__ v,
    u16* __restrict__ qh, u16* __restrict__ ql,
    u16* __restrict__ kh, u16* __restrict__ kl, u16* __restrict__ vh) {
    int i = blockIdx.x * 256 + threadIdx.x;
    int y = blockIdx.y;
    if (y == 2) { vh[i] = f2h(v[i]); return; }
    const float* s = y ? k : q;
    u16* h = y ? kh : qh;
    u16* l = y ? kl : ql;
    float val = s[i];
    u16 hh = f2bf(val);
    h[i] = hh;
    l[i] = f2bf(val - bf2f(hh));
}

// ---------------- prep: weights -> B^T [N][K] via LDS-tiled transpose ----------------
__global__ __launch_bounds__(256) void k_wprep(
    const float* __restrict__ Wq, const float* __restrict__ Wk,
    const float* __restrict__ Wv, const float* __restrict__ Wo,
    u16* __restrict__ WqTh, u16* __restrict__ WqTl,
    u16* __restrict__ WkTh, u16* __restrict__ WkTl,
    u16* __restrict__ WvT, u16* __restrict__ WoT) {
    __shared__ float Ts[64 * 65];
    const int y = blockIdx.y;
    const int ti = blockIdx.x >> 4, tj = blockIdx.x & 15;   // n-tile, k-tile
    const float* W = (y == 0) ? Wq : (y == 1) ? Wk : (y == 2) ? Wv : Wo;
    const int t = threadIdx.x;
    const int col = t & 63, rb = (t >> 6) * 16;
#pragma unroll
    for (int rr = 0; rr < 16; rr++) {
        int row = rb + rr;   // k-local
        float v = (y < 3) ? W[(size_t)ti * 65536 + (size_t)(tj * 64 + row) * 64 + col]
                          : W[(size_t)(tj * 64 + row) * Ee + ti * 64 + col];
        Ts[row * 65 + col] = v;
    }
    __syncthreads();
#pragma unroll
    for (int rr = 0; rr < 16; rr++) {
        int orow = rb + rr;  // n-local
        int ocol = col;      // k-local (coalesced)
        float v = Ts[ocol * 65 + orow];
        size_t oidx = (size_t)(ti * 64 + orow) * Ee + tj * 64 + ocol;
        if (y == 0) {
            u16 hh = f2bf(v); WqTh[oidx] = hh; WqTl[oidx] = f2bf(v - bf2f(hh));
        } else if (y == 1) {
            u16 hh = f2bf(v); WkTh[oidx] = hh; WkTl[oidx] = f2bf(v - bf2f(hh));
        } else if (y == 2) {
            WvT[oidx] = f2h(v);
        } else {
            WoT[oidx] = f2h(v);
        }
    }
}

// ---------------- GEMM body, 64(M) x 128(N) tile ----------------
// SPLIT=1: bf16 hi/lo 3-MFMA. F16=1: fp16 MFMA.
// OUTMODE: 0 = f32 row-major, 1 = fp16 transposed [N][M], 2 = bf16 hi/lo row-major.
template <int SPLIT, int F16, int OUTMODE>
DI void gemm_body(const u16* __restrict__ Ah, const u16* __restrict__ Al,
                  const u16* __restrict__ Bh, const u16* __restrict__ Bl,
                  const float* __restrict__ bias,
                  u16* __restrict__ C16h, u16* __restrict__ C16l, float* __restrict__ Cf,
                  float scale, u16* As0, u16* As1, u16* Bs0, u16* Bs1) {
    constexpr int M = Mrows, N = Ee, K = Ee;
    const int tid = threadIdx.x;
    const int wave = tid >> 6, lane = tid & 63;
    const int quad = lane >> 4, l16 = lane & 15;
    const int m0 = blockIdx.y * 64, n0 = blockIdx.x * 128;
    const int wm = (wave >> 1) * 32, wn = (wave & 1) * 64;

    f32x4 acc[2][4];
#pragma unroll
    for (int i = 0; i < 2; i++)
#pragma unroll
        for (int j = 0; j < 4; j++) acc[i][j] = (f32x4)0.0f;

    for (int kk = 0; kk < K; kk += 32) {
        __syncthreads();
        {   // A tile: 64 rows x 32 k = 256 chunks of 16B (lane-linear)
            int c = tid;
            int row = c >> 2, j = c & 3;
            size_t ga = (size_t)(m0 + row) * K + kk + j * 8;
            gld16(Ah + ga, As0 + c * 8);
            if constexpr (SPLIT) gld16(Al + ga, As1 + c * 8);
        }
#pragma unroll
        for (int i = 0; i < 2; i++) {  // B tile: 128 rows x 32 k = 512 chunks
            int c = tid + i * 256;
            int row = c >> 2, j = c & 3;
            size_t gb = (size_t)(n0 + row) * K + kk + j * 8;
            gld16(Bh + gb, Bs0 + c * 8);
            if constexpr (SPLIT) gld16(Bl + gb, Bs1 + c * 8);
        }
        __syncthreads();

        s16x8 af[2][2], bf[4][2];
#pragma unroll
        for (int mt = 0; mt < 2; mt++) {
            int r = wm + mt * 16 + l16;
            af[mt][0] = *(const s16x8*)&As0[r * 32 + quad * 8];
            if constexpr (SPLIT) af[mt][1] = *(const s16x8*)&As1[r * 32 + quad * 8];
        }
#pragma unroll
        for (int nt = 0; nt < 4; nt++) {
            int r = wn + nt * 16 + l16;
            bf[nt][0] = *(const s16x8*)&Bs0[r * 32 + quad * 8];
            if constexpr (SPLIT) bf[nt][1] = *(const s16x8*)&Bs1[r * 32 + quad * 8];
        }
#pragma unroll
        for (int mt = 0; mt < 2; mt++)
#pragma unroll
            for (int nt = 0; nt < 4; nt++) {
                if constexpr (F16) {
                    acc[mt][nt] = MFMA_F16(af[mt][0], bf[nt][0], acc[mt][nt]);
                } else {
                    acc[mt][nt] = MFMA_BF(af[mt][0], bf[nt][0], acc[mt][nt]);
                    if constexpr (SPLIT) {
                        acc[mt][nt] = MFMA_BF(af[mt][0], bf[nt][1], acc[mt][nt]);
                        acc[mt][nt] = MFMA_BF(af[mt][1], bf[nt][0], acc[mt][nt]);
                    }
                }
            }
    }

    // epilogue — C/D layout: col = lane&15, row = quad*4 + reg
#pragma unroll
    for (int mt = 0; mt < 2; mt++)
#pragma unroll
        for (int nt = 0; nt < 4; nt++) {
            int gn = n0 + wn + nt * 16 + l16;
            float bs = bias[gn];
            if constexpr (OUTMODE == 1) {
                int gm = m0 + wm + mt * 16 + quad * 4;
                u16x4 pk;
#pragma unroll
                for (int r = 0; r < 4; r++) pk[r] = f2h((acc[mt][nt][r] + bs) * scale);
                *(u16x4*)&C16h[(size_t)gn * M + gm] = pk;
            } else {
#pragma unroll
                for (int r = 0; r < 4; r++) {
                    int gm = m0 + wm + mt * 16 + quad * 4 + r;
                    float v = (acc[mt][nt][r] + bs) * scale;
                    if constexpr (OUTMODE == 0) {
                        Cf[(size_t)gm * N + gn] = v;
                    } else {
                        u16 hh = f2bf(v);
                        C16h[(size_t)gm * N + gn] = hh;
                        C16l[(size_t)gm * N + gn] = f2bf(v - bf2f(hh));
                    }
                }
            }
        }
}

// ---------------- fused Q/K/V projections (grid.z selects) ----------------
__global__ __launch_bounds__(256, 4) void k_qkv(
    const u16* __restrict__ qh, const u16* __restrict__ ql,
    const u16* __restrict__ kh, const u16* __restrict__ kl,
    const u16* __restrict__ vh,
    const u16* __restrict__ WqTh, const u16* __restrict__ WqTl,
    const u16* __restrict__ WkTh, const u16* __restrict__ WkTl,
    const u16* __restrict__ WvT,
    const float* __restrict__ bq, const float* __restrict__ bk, const float* __restrict__ bv,
    u16* __restrict__ Qh, u16* __restrict__ Ql2,
    u16* __restrict__ Kh, u16* __restrict__ Kl2, u16* __restrict__ Vt) {
    __shared__ u16 As[2][64 * 32];
    __shared__ u16 Bs[2][128 * 32];
    int z = blockIdx.z;
    if (z == 0)
        gemm_body<1, 0, 2>(qh, ql, WqTh, WqTl, bq, Qh, Ql2, nullptr, QSCALE,
                           As[0], As[1], Bs[0], Bs[1]);
    else if (z == 1)
        gemm_body<1, 0, 2>(kh, kl, WkTh, WkTl, bk, Kh, Kl2, nullptr, 1.0f,
                           As[0], As[1], Bs[0], Bs[1]);
    else
        gemm_body<0, 1, 1>(vh, nullptr, WvT, nullptr, bv, Vt, nullptr, nullptr, 1.0f,
                           As[0], As[1], Bs[0], Bs[1]);
}

// ---------------- output projection: ctx(fp16) @ WoT(fp16) + bo -> f32 ----------------
__global__ __launch_bounds__(256, 4) void k_out(
    const u16* __restrict__ ctx, const u16* __restrict__ WoT,
    const float* __restrict__ bo, float* __restrict__ out) {
    __shared__ u16 As[64 * 32];
    __shared__ u16 Bs[128 * 32];
    gemm_body<0, 1, 0>(ctx, nullptr, WoT, nullptr, bo, nullptr, nullptr, out, 1.0f,
                       As, nullptr, Bs, nullptr);
}

// ---------------- flash attention: 128q block, 32 q-cols/wave ----------------
// r7 model: LDS-pipe-bound (~85%). r8 lesson: cutting LDS traffic via cross-wave
// softmax costs more in barriers than it saves. This round: 32 q/wave in a 128q
// block — K-frag reads serve 2x the q (16 reads -> 48 QK MFMAs), staging per q
// halves, barriers stay 2/iter, softmax stays wave-local. LDS ~13 cyc/q vs r7 ~28.
// Score path: bf16 hi/lo split (r5: fp16 scores -> absmax 432). exp2 domain,
// QSCALE folded into Q projection. V/P/ctx fp16. Grid x = bh -> XCD=bh%8 L2 reuse
// (r8: FETCH 106->21 MB).
__global__ __launch_bounds__(256, 2) void k_attn(
    const u16* __restrict__ Qh, const u16* __restrict__ Ql,
    const u16* __restrict__ Kh, const u16* __restrict__ Kl,
    const u16* __restrict__ Vt, u16* __restrict__ ctx) {
    const int bh = blockIdx.x;
    const int b = bh >> 4, h = bh & 15;
    const int q0 = blockIdx.y * 128;
    const int rowBase = b * Ss + q0;
    const int hc = h * 64;

    __shared__ u16 Ks[2][64 * 64];     // [t][d] bf16 hi/lo, xor-swizzled (16 KB)
    __shared__ u16 Vs[64 * 64];        // [d][t] fp16, xor-swizzled (8 KB)
    __shared__ u16 Pw[4][32 * 72];     // per-wave [q 32][t 64], pad 72 (18.4 KB)

    const int tid = threadIdx.x;
    const int wave = tid >> 6, lane = tid & 63;
    const int quad = lane >> 4, l16 = lane & 15;

    // loop-invariant Q B-frags bq[nt][kc][hl] (lane n = q, k-contiguous 16B)
    s16x8 bq[2][2][2];
#pragma unroll
    for (int nt = 0; nt < 2; nt++) {
        int row = rowBase + wave * 32 + nt * 16 + l16;
#pragma unroll
        for (int kc = 0; kc < 2; kc++) {
            bq[nt][kc][0] = *(const s16x8*)(Qh + (size_t)row * Ee + hc + kc * 32 + quad * 8);
            bq[nt][kc][1] = *(const s16x8*)(Ql + (size_t)row * Ee + hc + kc * 32 + quad * 8);
        }
    }

    f32x4 o[2][4];   // [nt][dg]: O[d=dg*16+quad*4+r][q=wave*32+nt*16+l16]
#pragma unroll
    for (int nt = 0; nt < 2; nt++)
#pragma unroll
        for (int dg = 0; dg < 4; dg++) o[nt][dg] = (f32x4)0.0f;
    float m_[2] = {-1e30f, -1e30f};
    float l_[2] = {0.f, 0.f};

    for (int t0 = 0; t0 < Ss; t0 += 64) {
        const int kRowBase = b * Ss + t0;
        __syncthreads();
#pragma unroll
        for (int i = 0; i < 2; i++) {
            int c = tid + i * 256;
            int row = c >> 3, j = c & 7;
            int sj = j ^ (row & 7);
            *(s16x8*)&Ks[0][row * 64 + sj * 8] =
                *(const s16x8*)(Kh + (size_t)(kRowBase + row) * Ee + hc + j * 8);
            *(s16x8*)&Ks[1][row * 64 + sj * 8] =
                *(const s16x8*)(Kl + (size_t)(kRowBase + row) * Ee + hc + j * 8);
            *(s16x8*)&Vs[row * 64 + sj * 8] =
                *(const s16x8*)(Vt + (size_t)(hc + row) * Mrows + kRowBase + j * 8);
        }
        __syncthreads();

        // S^T = K·Q^T (split); st[nt][mt]: t = mt*16 + quad*4 + r, q-col = nt tile, l16
        f32x4 st[2][4];
#pragma unroll
        for (int nt = 0; nt < 2; nt++)
#pragma unroll
            for (int mt = 0; mt < 4; mt++) st[nt][mt] = (f32x4)0.0f;
#pragma unroll
        for (int mt = 0; mt < 4; mt++) {
            int tr = mt * 16 + l16;
#pragma unroll
            for (int kc = 0; kc < 2; kc++) {
                int sj = (kc * 4 + quad) ^ (l16 & 7);
                s16x8 akh = *(const s16x8*)&Ks[0][tr * 64 + sj * 8];
                s16x8 akl = *(const s16x8*)&Ks[1][tr * 64 + sj * 8];
#pragma unroll
                for (int nt = 0; nt < 2; nt++) {
                    st[nt][mt] = MFMA_BF(akh, bq[nt][kc][0], st[nt][mt]);
                    st[nt][mt] = MFMA_BF(akh, bq[nt][kc][1], st[nt][mt]);
                    st[nt][mt] = MFMA_BF(akl, bq[nt][kc][0], st[nt][mt]);
                }
            }
        }

        // online softmax per q-column (2 per lane), exp2 domain, wave-local
#pragma unroll
        for (int nt = 0; nt < 2; nt++) {
            float t01 = fmaxf(fmaxf(st[nt][0][0], st[nt][0][1]), fmaxf(st[nt][0][2], st[nt][0][3]));
            float t23 = fmaxf(fmaxf(st[nt][1][0], st[nt][1][1]), fmaxf(st[nt][1][2], st[nt][1][3]));
            float t45 = fmaxf(fmaxf(st[nt][2][0], st[nt][2][1]), fmaxf(st[nt][2][2], st[nt][2][3]));
            float t67 = fmaxf(fmaxf(st[nt][3][0], st[nt][3][1]), fmaxf(st[nt][3][2], st[nt][3][3]));
            float tmax = fmaxf(fmaxf(t01, t23), fmaxf(t45, t67));
            tmax = fmaxf(tmax, __shfl_xor(tmax, 16));
            tmax = fmaxf(tmax, __shfl_xor(tmax, 32));
            float mnew = fmaxf(m_[nt], tmax);
            float al = ex2(m_[nt] - mnew);
            m_[nt] = mnew;
            float psum = 0.f;
#pragma unroll
            for (int mt = 0; mt < 4; mt++) {
                float p0 = ex2(st[nt][mt][0] - mnew);
                float p1 = ex2(st[nt][mt][1] - mnew);
                float p2 = ex2(st[nt][mt][2] - mnew);
                float p3 = ex2(st[nt][mt][3] - mnew);
                psum += (p0 + p1) + (p2 + p3);
                u32x2 pk;
                pk[0] = pkrtz(p0, p1);
                pk[1] = pkrtz(p2, p3);
                *(u32x2*)&Pw[wave][(nt * 16 + l16) * 72 + mt * 16 + quad * 4] = pk;
            }
            psum += __shfl_xor(psum, 16);
            psum += __shfl_xor(psum, 32);
            l_[nt] = l_[nt] * al + psum;
#pragma unroll
            for (int dg = 0; dg < 4; dg++) o[nt][dg] *= al;
        }

        // O^T += V^T P^T  (A = Vs[d][t], B = Pw[q][t], wave-private)
#pragma unroll
        for (int kc = 0; kc < 2; kc++) {
            s16x8 bp[2];
#pragma unroll
            for (int nt = 0; nt < 2; nt++)
                bp[nt] = *(const s16x8*)&Pw[wave][(nt * 16 + l16) * 72 + kc * 32 + quad * 8];
#pragma unroll
            for (int dg = 0; dg < 4; dg++) {
                int sj = (kc * 4 + quad) ^ (l16 & 7);
                s16x8 av = *(const s16x8*)&Vs[(dg * 16 + l16) * 64 + sj * 8];
#pragma unroll
                for (int nt = 0; nt < 2; nt++) o[nt][dg] = MFMA_F16(av, bp[nt], o[nt][dg]);
            }
        }
    }

    // epilogue: ctx[q][hc+d] fp16, d = dg*16 + quad*4 + r  -> 8B packed stores
#pragma unroll
    for (int nt = 0; nt < 2; nt++) {
        float inv = 1.0f / l_[nt];
        int gm = rowBase + wave * 32 + nt * 16 + l16;
#pragma unroll
        for (int dg = 0; dg < 4; dg++) {
            u32x2 pk;
            pk[0] = pkrtz(o[nt][dg][0] * inv, o[nt][dg][1] * inv);
            pk[1] = pkrtz(o[nt][dg][2] * inv, o[nt][dg][3] * inv);
            *(u32x2*)&ctx[(size_t)gm * Ee + hc + dg * 16 + quad * 4] = pk;
        }
    }
}

extern "C" void kernel_launch(void* const* d_in, const int* in_sizes, int n_in,
                              void* d_out, int out_size, void* d_ws, size_t ws_size,
                              hipStream_t stream) {
    const float* q   = (const float*)d_in[0];
    const float* kin = (const float*)d_in[1];
    const float* v   = (const float*)d_in[2];
    const float* Wq  = (const float*)d_in[3];
    const float* Wk  = (const float*)d_in[4];
    const float* Wv  = (const float*)d_in[5];
    const float* bq  = (const float*)d_in[6];
    const float* bk  = (const float*)d_in[7];
    const float* bv  = (const float*)d_in[8];
    const float* Wo  = (const float*)d_in[9];
    const float* bo  = (const float*)d_in[10];

    u16* ws = (u16*)d_ws;
    u16 *qh = ws,          *ql = ws + NE,     *kh = ws + 2 * NE, *kl = ws + 3 * NE;
    u16 *vh = ws + 4 * NE;
    u16 *Qh = ws + 5 * NE, *Ql = ws + 6 * NE, *Kh = ws + 7 * NE, *Kl = ws + 8 * NE;
    u16 *Vt = ws + 9 * NE, *ctx = ws + 10 * NE;
    u16 *WqTh = ws + 11 * NE;
    u16 *WqTl = WqTh + WN, *WkTh = WqTh + 2 * WN, *WkTl = WqTh + 3 * WN;
    u16 *WvT = WqTh + 4 * WN, *WoT = WqTh + 5 * WN;

    dim3 b256(256);
    k_split3<<<dim3(NE / 256, 3), b256, 0, stream>>>(q, kin, v, qh, ql, kh, kl, vh);
    k_wprep<<<dim3(256, 4), b256, 0, stream>>>(Wq, Wk, Wv, Wo,
                                               WqTh, WqTl, WkTh, WkTl, WvT, WoT);

    k_qkv<<<dim3(8, 64, 3), b256, 0, stream>>>(qh, ql, kh, kl, vh,
                                               WqTh, WqTl, WkTh, WkTl, WvT,
                                               bq, bk, bv, Qh, Ql, Kh, Kl, Vt);

    k_attn<<<dim3(Bb * Hh, Ss / 128), b256, 0, stream>>>(Qh, Ql, Kh, Kl, Vt, ctx);

    k_out<<<dim3(8, 64), b256, 0, stream>>>(ctx, WoT, bo, (float*)d_out);
}